// Round 1
// baseline (279.755 us; speedup 1.0000x reference)
//
#include <hip/hip_runtime.h>

typedef unsigned short u16;
typedef __attribute__((ext_vector_type(8))) short short8;
typedef __attribute__((ext_vector_type(4))) float f32x4;

#define NB 2
#define NSEQ 2048
#define DIM 768
#define NH 12
#define HDIM 64
#define SCALE 0.125f

__device__ __forceinline__ u16 f2bf(float x) {
    union { float f; unsigned u; } v; v.f = x;
    unsigned r = v.u + 0x7fffu + ((v.u >> 16) & 1u);
    return (u16)(r >> 16);
}

__device__ __forceinline__ f32x4 mfma16(short8 a, short8 b, f32x4 c) {
    return __builtin_amdgcn_mfma_f32_16x16x32_bf16(a, b, c, 0, 0, 0);
}

// ---------------- prep kernels ----------------

__global__ __launch_bounds__(256) void convert_x(const float* __restrict__ in,
                                                 u16* __restrict__ outp) {
    int i = (blockIdx.x * 256 + threadIdx.x) * 4;
    float4 v = *(const float4*)(in + i);
    unsigned r0 = (unsigned)f2bf(v.x) | ((unsigned)f2bf(v.y) << 16);
    unsigned r1 = (unsigned)f2bf(v.z) | ((unsigned)f2bf(v.w) << 16);
    *(uint2*)(outp + i) = make_uint2(r0, r1);
}

// in: [rows][cols] fp32 ; out: [cols][rows] bf16
__global__ __launch_bounds__(256) void transpose_to_bf16(const float* __restrict__ in,
                                                         u16* __restrict__ outp,
                                                         int rows, int cols) {
    __shared__ float tile[32][33];
    int c0 = blockIdx.x * 32, r0 = blockIdx.y * 32;
    int tx = threadIdx.x & 31, ty = threadIdx.x >> 5;  // 32 x 8
    #pragma unroll
    for (int i = 0; i < 32; i += 8)
        tile[ty + i][tx] = in[(size_t)(r0 + ty + i) * cols + c0 + tx];
    __syncthreads();
    #pragma unroll
    for (int i = 0; i < 32; i += 8)
        outp[(size_t)(c0 + ty + i) * rows + r0 + tx] = f2bf(tile[tx][ty + i]);
}

// ---------------- QKV GEMM ----------------
// C[4096][2304] = A[4096][768] @ BT[2304][768]^T + bias
// scatter: w=0 -> q[b][h][n][hd], w=1 -> k[b][h][n][hd], w=2 -> vT[b][h][hd][n]
__global__ __launch_bounds__(256) void gemm_qkv(const u16* __restrict__ A,
                                                const u16* __restrict__ BT,
                                                const float* __restrict__ bias,
                                                u16* __restrict__ qo,
                                                u16* __restrict__ ko,
                                                u16* __restrict__ vo) {
    const int K = DIM;
    __shared__ u16 As[128][32];
    __shared__ u16 Bs[128][32];
    const int bm = blockIdx.y * 128, bn = blockIdx.x * 128;
    const int t = threadIdx.x;
    const int lane = t & 63, wave = t >> 6;
    const int l15 = lane & 15, quad = lane >> 4;
    const int wm = (wave >> 1) * 64, wn = (wave & 1) * 64;
    const int lr = t >> 2;          // staging row 0..63
    const int lc = (t & 3) * 8;     // staging col offset

    f32x4 acc[4][4] = {};

    for (int k0 = 0; k0 < K; k0 += 32) {
        __syncthreads();
        *(uint4*)&As[lr][lc]      = *(const uint4*)&A[(size_t)(bm + lr) * K + k0 + lc];
        *(uint4*)&As[lr + 64][lc] = *(const uint4*)&A[(size_t)(bm + lr + 64) * K + k0 + lc];
        *(uint4*)&Bs[lr][lc]      = *(const uint4*)&BT[(size_t)(bn + lr) * K + k0 + lc];
        *(uint4*)&Bs[lr + 64][lc] = *(const uint4*)&BT[(size_t)(bn + lr + 64) * K + k0 + lc];
        __syncthreads();
        short8 af[4], bf[4];
        #pragma unroll
        for (int i = 0; i < 4; i++) af[i] = *(const short8*)&As[wm + i * 16 + l15][quad * 8];
        #pragma unroll
        for (int j = 0; j < 4; j++) bf[j] = *(const short8*)&Bs[wn + j * 16 + l15][quad * 8];
        #pragma unroll
        for (int i = 0; i < 4; i++)
            #pragma unroll
            for (int j = 0; j < 4; j++)
                acc[i][j] = mfma16(af[i], bf[j], acc[i][j]);
    }

    #pragma unroll
    for (int i = 0; i < 4; i++) {
        int mbase = bm + wm + i * 16 + quad * 4;
        #pragma unroll
        for (int j = 0; j < 4; j++) {
            int ncol = bn + wn + j * 16 + l15;
            int w = ncol / DIM, rem = ncol % DIM;
            int h = rem >> 6, hd = rem & 63;
            float bb = bias[ncol];
            #pragma unroll
            for (int r = 0; r < 4; r++) {
                int m = mbase + r;
                int b = m >> 11, nn = m & 2047;
                u16 bv = f2bf(acc[i][j][r] + bb);
                if (w == 2) {
                    vo[(((size_t)(b * NH + h)) * HDIM + hd) * NSEQ + nn] = bv;
                } else {
                    size_t idx = (((size_t)(b * NH + h)) * NSEQ + nn) * HDIM + hd;
                    if (w == 0) qo[idx] = bv; else ko[idx] = bv;
                }
            }
        }
    }
}

// ---------------- fused region-gated flash attention ----------------
// grid: (N/64, B*H); 4 waves, each wave owns 16 query rows
__global__ __launch_bounds__(256) void attn_kernel(const u16* __restrict__ Q,
                                                   const u16* __restrict__ Kg,
                                                   const u16* __restrict__ Vt,
                                                   const float* __restrict__ masks,
                                                   const float* __restrict__ lambda_r,
                                                   const float* __restrict__ theta_r,
                                                   const float* __restrict__ mask_w,
                                                   u16* __restrict__ AO) {
    const int bh = blockIdx.y;
    const int b = bh / NH, h = bh % NH;
    const int qb = blockIdx.x * 64;
    const int t = threadIdx.x, wave = t >> 6, lane = t & 63;
    const int l15 = lane & 15, quad = lane >> 4;

    __shared__ u16 Ks[64][72];       // [key][d], padded (+16B) for bank spread
    __shared__ u16 Vs[64][72];       // [d][key], padded
    __shared__ float mks[64];
    __shared__ u16 Ps[4][16][72];    // per-wave P tile [q][key], padded

    const size_t base = (size_t)bh * (NSEQ * HDIM);
    const int qrow = qb + wave * 16;

    short8 aq0 = *(const short8*)&Q[base + (size_t)(qrow + l15) * HDIM + quad * 8];
    short8 aq1 = *(const short8*)&Q[base + (size_t)(qrow + l15) * HDIM + 32 + quad * 8];

    const float lam = lambda_r[bh], th = theta_r[bh], mw = mask_w[bh];
    float mq[4];
    #pragma unroll
    for (int r = 0; r < 4; r++) mq[r] = masks[bh * NSEQ + qrow + quad * 4 + r];

    float m_run[4], l_run[4];
    #pragma unroll
    for (int r = 0; r < 4; r++) { m_run[r] = -1e30f; l_run[r] = 0.f; }
    f32x4 O[4] = {};

    const int srow = t >> 3;         // 0..31
    const int scol = (t & 7) * 8;    // 0..56

    for (int kt = 0; kt < NSEQ / 64; kt++) {
        const int krow = kt * 64;
        __syncthreads();
        *(uint4*)&Ks[srow][scol]      = *(const uint4*)&Kg[base + (size_t)(krow + srow) * HDIM + scol];
        *(uint4*)&Ks[srow + 32][scol] = *(const uint4*)&Kg[base + (size_t)(krow + srow + 32) * HDIM + scol];
        *(uint4*)&Vs[srow][scol]      = *(const uint4*)&Vt[base + (size_t)srow * NSEQ + krow + scol];
        *(uint4*)&Vs[srow + 32][scol] = *(const uint4*)&Vt[base + (size_t)(srow + 32) * NSEQ + krow + scol];
        if (t < 64) mks[t] = masks[bh * NSEQ + krow + t];
        __syncthreads();

        // scores for 4 chunks of 16 keys
        float sv[4][4];
        #pragma unroll
        for (int c = 0; c < 4; c++) {
            short8 bk0 = *(const short8*)&Ks[c * 16 + l15][quad * 8];
            short8 bk1 = *(const short8*)&Ks[c * 16 + l15][32 + quad * 8];
            f32x4 S = {0.f, 0.f, 0.f, 0.f};
            S = mfma16(aq0, bk0, S);
            S = mfma16(aq1, bk1, S);
            float mkc = mks[c * 16 + l15];
            #pragma unroll
            for (int r = 0; r < 4; r++) {
                float s = S[r] * SCALE;
                float g = 1.f / (1.f + __expf(-lam * (mq[r] * mkc - th)));
                sv[c][r] = s * g;
            }
        }
        // online softmax over this 64-key tile
        float cm[4];
        #pragma unroll
        for (int r = 0; r < 4; r++)
            cm[r] = fmaxf(fmaxf(sv[0][r], sv[1][r]), fmaxf(sv[2][r], sv[3][r]));
        #pragma unroll
        for (int off = 1; off < 16; off <<= 1)
            #pragma unroll
            for (int r = 0; r < 4; r++)
                cm[r] = fmaxf(cm[r], __shfl_xor(cm[r], off));
        float alpha[4], rs[4];
        #pragma unroll
        for (int r = 0; r < 4; r++) {
            float nm = fmaxf(m_run[r], cm[r]);
            alpha[r] = __expf(m_run[r] - nm);
            m_run[r] = nm;
            rs[r] = 0.f;
        }
        #pragma unroll
        for (int c = 0; c < 4; c++)
            #pragma unroll
            for (int r = 0; r < 4; r++) {
                float p = __expf(sv[c][r] - m_run[r]);
                rs[r] += p;
                Ps[wave][quad * 4 + r][c * 16 + l15] = f2bf(p);
            }
        #pragma unroll
        for (int off = 1; off < 16; off <<= 1)
            #pragma unroll
            for (int r = 0; r < 4; r++)
                rs[r] += __shfl_xor(rs[r], off);
        #pragma unroll
        for (int r = 0; r < 4; r++) l_run[r] = l_run[r] * alpha[r] + rs[r];
        #pragma unroll
        for (int dt = 0; dt < 4; dt++)
            #pragma unroll
            for (int r = 0; r < 4; r++) O[dt][r] *= alpha[r];

        // PV: O[q][d] += P[q][key] * V[key][d]
        #pragma unroll
        for (int kc = 0; kc < 2; kc++) {
            short8 ap = *(const short8*)&Ps[wave][l15][kc * 32 + quad * 8];
            #pragma unroll
            for (int dt = 0; dt < 4; dt++) {
                short8 bv = *(const short8*)&Vs[dt * 16 + l15][kc * 32 + quad * 8];
                O[dt] = mfma16(ap, bv, O[dt]);
            }
        }
    }

    float sc[4];
    #pragma unroll
    for (int r = 0; r < 4; r++) sc[r] = mw / l_run[r];
    #pragma unroll
    for (int dt = 0; dt < 4; dt++)
        #pragma unroll
        for (int r = 0; r < 4; r++) {
            float val = O[dt][r] * sc[r];
            size_t idx = ((size_t)b * NSEQ + qrow + quad * 4 + r) * DIM + h * HDIM + dt * 16 + l15;
            AO[idx] = f2bf(val);
        }
}

// ---------------- output projection GEMM ----------------
__global__ __launch_bounds__(256) void gemm_proj(const u16* __restrict__ A,
                                                 const u16* __restrict__ BT,
                                                 const float* __restrict__ bias,
                                                 float* __restrict__ outp) {
    const int K = DIM;
    __shared__ u16 As[128][32];
    __shared__ u16 Bs[128][32];
    const int bm = blockIdx.y * 128, bn = blockIdx.x * 128;
    const int t = threadIdx.x;
    const int lane = t & 63, wave = t >> 6;
    const int l15 = lane & 15, quad = lane >> 4;
    const int wm = (wave >> 1) * 64, wn = (wave & 1) * 64;
    const int lr = t >> 2;
    const int lc = (t & 3) * 8;

    f32x4 acc[4][4] = {};

    for (int k0 = 0; k0 < K; k0 += 32) {
        __syncthreads();
        *(uint4*)&As[lr][lc]      = *(const uint4*)&A[(size_t)(bm + lr) * K + k0 + lc];
        *(uint4*)&As[lr + 64][lc] = *(const uint4*)&A[(size_t)(bm + lr + 64) * K + k0 + lc];
        *(uint4*)&Bs[lr][lc]      = *(const uint4*)&BT[(size_t)(bn + lr) * K + k0 + lc];
        *(uint4*)&Bs[lr + 64][lc] = *(const uint4*)&BT[(size_t)(bn + lr + 64) * K + k0 + lc];
        __syncthreads();
        short8 af[4], bf[4];
        #pragma unroll
        for (int i = 0; i < 4; i++) af[i] = *(const short8*)&As[wm + i * 16 + l15][quad * 8];
        #pragma unroll
        for (int j = 0; j < 4; j++) bf[j] = *(const short8*)&Bs[wn + j * 16 + l15][quad * 8];
        #pragma unroll
        for (int i = 0; i < 4; i++)
            #pragma unroll
            for (int j = 0; j < 4; j++)
                acc[i][j] = mfma16(af[i], bf[j], acc[i][j]);
    }

    #pragma unroll
    for (int i = 0; i < 4; i++) {
        int mbase = bm + wm + i * 16 + quad * 4;
        #pragma unroll
        for (int j = 0; j < 4; j++) {
            int ncol = bn + wn + j * 16 + l15;
            float bb = bias[ncol];
            #pragma unroll
            for (int r = 0; r < 4; r++)
                outp[(size_t)(mbase + r) * DIM + ncol] = acc[i][j][r] + bb;
        }
    }
}

// ---------------- launch ----------------
extern "C" void kernel_launch(void* const* d_in, const int* in_sizes, int n_in,
                              void* d_out, int out_size, void* d_ws, size_t ws_size,
                              hipStream_t stream) {
    const float* x            = (const float*)d_in[0];
    const float* masks        = (const float*)d_in[1];
    const float* lambda_r     = (const float*)d_in[2];
    const float* theta_r      = (const float*)d_in[3];
    const float* mask_weights = (const float*)d_in[4];
    const float* qkv_w        = (const float*)d_in[5];
    const float* qkv_b        = (const float*)d_in[6];
    const float* proj_w       = (const float*)d_in[7];
    const float* proj_b       = (const float*)d_in[8];
    float* outp = (float*)d_out;

    u16* xb    = (u16*)d_ws;                                 // 4096*768
    u16* wqkvT = xb    + (size_t)4096 * 768;                 // 2304*768
    u16* wprT  = wqkvT + (size_t)2304 * 768;                 // 768*768
    u16* qg    = wprT  + (size_t)768 * 768;                  // 24*2048*64
    u16* kg    = qg    + (size_t)NB * NH * NSEQ * HDIM;
    u16* vt    = kg    + (size_t)NB * NH * NSEQ * HDIM;
    u16* ao    = vt    + (size_t)NB * NH * NSEQ * HDIM;      // 4096*768

    convert_x<<<dim3((4096 * 768) / (4 * 256)), 256, 0, stream>>>(x, xb);
    transpose_to_bf16<<<dim3(2304 / 32, 768 / 32), 256, 0, stream>>>(qkv_w, wqkvT, 768, 2304);
    transpose_to_bf16<<<dim3(768 / 32, 768 / 32), 256, 0, stream>>>(proj_w, wprT, 768, 768);
    gemm_qkv<<<dim3(2304 / 128, 4096 / 128), 256, 0, stream>>>(xb, wqkvT, qkv_b, qg, kg, vt);
    attn_kernel<<<dim3(NSEQ / 64, NB * NH), 256, 0, stream>>>(qg, kg, vt, masks, lambda_r,
                                                              theta_r, mask_weights, ao);
    gemm_proj<<<dim3(768 / 128, 4096 / 128), 256, 0, stream>>>(ao, wprT, proj_b, outp);
}

// Round 2
// 197.299 us; speedup vs baseline: 1.4179x; 1.4179x over previous
//
#include <hip/hip_runtime.h>

typedef unsigned short u16;
typedef unsigned int u32;
typedef __attribute__((ext_vector_type(8))) short short8;
typedef __attribute__((ext_vector_type(4))) float f32x4;

#define NB 2
#define NSEQ 2048
#define DIM 768
#define NH 12
#define HDIM 64

// exp2 path: fold 0.125*log2(e) into the gate LUT so softmax exp is a single v_exp_f32
#if defined(__has_builtin)
#if __has_builtin(__builtin_amdgcn_exp2f)
#define EXPB(x) __builtin_amdgcn_exp2f(x)
#define CFOLD 0.18033688f  /* 0.125 * log2(e) */
#define HAVE_EXP2 1
#endif
#if __has_builtin(__builtin_amdgcn_fractf)
#define FRACT(x) __builtin_amdgcn_fractf(x)
#endif
#endif
#ifndef HAVE_EXP2
#define EXPB(x) __expf(x)
#define CFOLD 0.125f
#endif
#ifndef FRACT
#define FRACT(x) ((x) - floorf(x))
#endif

__device__ __forceinline__ u16 f2bf(float x) {
    union { float f; unsigned u; } v; v.f = x;
    unsigned r = v.u + 0x7fffu + ((v.u >> 16) & 1u);
    return (u16)(r >> 16);
}

// pack two floats as bf16 pair (RTNE) via v_add3-ish + v_perm
__device__ __forceinline__ u32 pack_bf16(float a, float b) {
    union { float f; u32 u; } A, B; A.f = a; B.f = b;
    u32 ra = A.u + 0x7fffu + ((A.u >> 16) & 1u);
    u32 rb = B.u + 0x7fffu + ((B.u >> 16) & 1u);
    return __builtin_amdgcn_perm(rb, ra, 0x07060302u);  // lo16 = hi(ra), hi16 = hi(rb)
}

__device__ __forceinline__ f32x4 mfma16(short8 a, short8 b, f32x4 c) {
    return __builtin_amdgcn_mfma_f32_16x16x32_bf16(a, b, c, 0, 0, 0);
}

// async global->LDS, 16B per lane, LDS dest = wave-uniform base + lane*16
__device__ __forceinline__ void glds16(const u16* g, u16* l) {
    __builtin_amdgcn_global_load_lds((const __attribute__((address_space(1))) u32*)g,
                                     (__attribute__((address_space(3))) u32*)l, 16, 0, 0);
}

// ---------------- prep kernels ----------------

__global__ __launch_bounds__(256) void convert_x(const float* __restrict__ in,
                                                 u16* __restrict__ outp) {
    int i = (blockIdx.x * 256 + threadIdx.x) * 4;
    float4 v = *(const float4*)(in + i);
    *(uint2*)(outp + i) = make_uint2(pack_bf16(v.x, v.y), pack_bf16(v.z, v.w));
}

// in: [rows][cols] fp32 ; out: [cols][rows] bf16
__global__ __launch_bounds__(256) void transpose_to_bf16(const float* __restrict__ in,
                                                         u16* __restrict__ outp,
                                                         int rows, int cols) {
    __shared__ float tile[32][33];
    int c0 = blockIdx.x * 32, r0 = blockIdx.y * 32;
    int tx = threadIdx.x & 31, ty = threadIdx.x >> 5;  // 32 x 8
    #pragma unroll
    for (int i = 0; i < 32; i += 8)
        tile[ty + i][tx] = in[(size_t)(r0 + ty + i) * cols + c0 + tx];
    __syncthreads();
    #pragma unroll
    for (int i = 0; i < 32; i += 8)
        outp[(size_t)(c0 + ty + i) * rows + r0 + tx] = f2bf(tile[tx][ty + i]);
}

// V [bh][n][64] -> V^T [bh][64][n]
__global__ __launch_bounds__(256) void vtrans(const u16* __restrict__ vin,
                                              u16* __restrict__ vout) {
    __shared__ __align__(16) u16 tile[64][72];
    const int bh = blockIdx.y;
    const int n0 = blockIdx.x * 64;
    const int t = threadIdx.x;
    const size_t base = (size_t)bh * NSEQ * HDIM;
    int r = t >> 3, cb = (t & 7) * 8;
    *(uint4*)&tile[r][cb]      = *(const uint4*)&vin[base + (size_t)(n0 + r) * HDIM + cb];
    *(uint4*)&tile[r + 32][cb] = *(const uint4*)&vin[base + (size_t)(n0 + r + 32) * HDIM + cb];
    __syncthreads();
    #pragma unroll
    for (int half = 0; half < 2; half++) {
        int d = (t >> 3) + half * 32;
        int nb = (t & 7) * 8;
        short8 v;
        #pragma unroll
        for (int j = 0; j < 8; j++) v[j] = (short)tile[nb + j][d];
        *(short8*)&vout[base + (size_t)d * NSEQ + n0 + nb] = v;
    }
}

// ---------------- QKV GEMM ----------------
// C[4096][2304] = A[4096][768] @ BT[2304][768]^T + bias; q,k,v all -> [bh][n][64]
__global__ __launch_bounds__(256) void gemm_qkv(const u16* __restrict__ A,
                                                const u16* __restrict__ BT,
                                                const float* __restrict__ bias,
                                                u16* __restrict__ qo,
                                                u16* __restrict__ ko,
                                                u16* __restrict__ vo) {
    __shared__ __align__(16) u16 As[128 * 32];
    __shared__ __align__(16) u16 Bs[128 * 32];
    const int bm = blockIdx.y * 128, bn = blockIdx.x * 128;
    const int t = threadIdx.x;
    const int lane = t & 63, wave = t >> 6;
    const int l15 = lane & 15, quad = lane >> 4;
    const int wm = (wave >> 1) * 64, wn = (wave & 1) * 64;

    const u16* ga = A + (size_t)(bm + (t >> 2)) * DIM + (t & 3) * 8;
    const u16* gb = BT + (size_t)(bn + (t >> 2)) * DIM + (t & 3) * 8;
    u16* la = As + wave * 512;
    u16* lb = Bs + wave * 512;

    f32x4 acc[4][4] = {};
    for (int k0 = 0; k0 < DIM; k0 += 32) {
        __syncthreads();
        glds16(ga, la);
        glds16(ga + (size_t)64 * DIM, la + 2048);
        glds16(gb, lb);
        glds16(gb + (size_t)64 * DIM, lb + 2048);
        ga += 32; gb += 32;
        __syncthreads();
        short8 af[4], bf[4];
        #pragma unroll
        for (int i = 0; i < 4; i++) af[i] = *(const short8*)&As[(wm + i * 16 + l15) * 32 + quad * 8];
        #pragma unroll
        for (int j = 0; j < 4; j++) bf[j] = *(const short8*)&Bs[(wn + j * 16 + l15) * 32 + quad * 8];
        #pragma unroll
        for (int i = 0; i < 4; i++)
            #pragma unroll
            for (int j = 0; j < 4; j++)
                acc[i][j] = mfma16(af[i], bf[j], acc[i][j]);
    }

    #pragma unroll
    for (int i = 0; i < 4; i++) {
        int mr = bm + wm + i * 16 + quad * 4;
        int b = mr >> 11, nn = mr & 2047;
        #pragma unroll
        for (int j = 0; j < 4; j++) {
            int ncol = bn + wn + j * 16 + l15;
            int w = ncol / DIM, rem = ncol - w * DIM;
            int h = rem >> 6, hd = rem & 63;
            u16* dst = (w == 0) ? qo : (w == 1) ? ko : vo;
            float bb = bias[ncol];
            size_t idx = (((size_t)(b * NH + h)) * NSEQ + nn) * HDIM + hd;
            #pragma unroll
            for (int r = 0; r < 4; r++)
                dst[idx + (size_t)r * HDIM] = f2bf(acc[i][j][r] + bb);
        }
    }
}

// ---------------- fused region-gated attention (S^T form, no-max softmax, gate LUT) ----
// grid: (N/64, B*H); 4 waves, each wave owns 16 query rows (q = lane&15)
__global__ __launch_bounds__(256) void attn_kernel(const u16* __restrict__ Q,
                                                   const u16* __restrict__ Kg,
                                                   const u16* __restrict__ Vt,
                                                   const float* __restrict__ masks,
                                                   const float* __restrict__ lambda_r,
                                                   const float* __restrict__ theta_r,
                                                   const float* __restrict__ mask_w,
                                                   u16* __restrict__ AO) {
    const int bh = blockIdx.y;
    const int b = bh / NH, h = bh % NH;
    const int qb = blockIdx.x * 64;
    const int t = threadIdx.x, wave = t >> 6, lane = t & 63;
    const int l15 = lane & 15, quad = lane >> 4;

    __shared__ __align__(16) u16 Ks[64 * 64];     // [key][d], XOR-swizzled 16B blocks
    __shared__ __align__(16) u16 Vs[64 * 64];     // [d][key], XOR-swizzled 16B blocks
    __shared__ __align__(16) u16 Ps[4][16 * 72];  // per-wave P [q][key], padded rows
    __shared__ __align__(16) float mks[64];
    __shared__ float gt[1026];
    __shared__ __align__(8) float2 ptab[1025];

    const float lam = lambda_r[bh], th = theta_r[bh], mw = mask_w[bh];

    // gate LUT over u = mq*mk in [0,1): g(u)*CFOLD, lerp pairs
    for (int i = t; i < 1026; i += 256) {
        float u = i * (1.0f / 1024.0f);
        float z = lam * (u - th);
        gt[i] = (1.0f / (1.0f + __expf(-z))) * CFOLD;
    }
    __syncthreads();
    for (int i = t; i < 1025; i += 256) {
        float a = gt[i];
        ptab[i] = make_float2(a, gt[i + 1] - a);
    }

    const size_t base = (size_t)bh * (NSEQ * HDIM);
    const int qrow = qb + wave * 16;

    // Q fragments (B operand: n=q=l15, k=d)
    const u16* Qr = Q + base + (size_t)(qrow + l15) * HDIM;
    short8 bq0 = *(const short8*)(Qr + quad * 8);
    short8 bq1 = *(const short8*)(Qr + 32 + quad * 8);
    const float mq1024 = masks[bh * NSEQ + qrow + l15] * 1024.0f;

    // staging pointers (swizzled source column-block)
    const int srow = t >> 3, scb = t & 7;
    const int gcb = scb ^ (srow & 7);
    const u16* kgp = Kg + base + (size_t)srow * HDIM + gcb * 8;
    const u16* vgp = Vt + base + (size_t)srow * NSEQ + gcb * 8;
    u16* ksl = Ks + wave * 512;
    u16* vsl = Vs + wave * 512;

    // hoisted fragment offsets
    const int ph = (quad ^ (l15 & 7)) * 8;
    const int kb0 = l15 * 64 + ph, kb1 = l15 * 64 + (ph ^ 32);
    u16* PsW = Ps[wave];
    const int pw = l15 * 72 + quad * 4;   // P write base (u16)
    const int prd = l15 * 72 + quad * 8;  // P read base (u16)

    float ls0 = 0.f, ls1 = 0.f, ls2 = 0.f, ls3 = 0.f;
    f32x4 O[4] = {};

    for (int kt = 0; kt < NSEQ / 64; kt++) {
        __syncthreads();
        glds16(kgp, ksl);
        glds16(kgp + 2048, ksl + 2048);
        glds16(vgp, vsl);
        glds16(vgp + (size_t)32 * NSEQ, vsl + 2048);
        if (t < 16) *(float4*)&mks[t * 4] = *(const float4*)&masks[bh * NSEQ + kt * 64 + t * 4];
        kgp += 4096; vgp += 64;
        __syncthreads();

        #pragma unroll
        for (int c = 0; c < 4; c++) {
            short8 ak0 = *(const short8*)&Ks[kb0 + c * 1024];
            short8 ak1 = *(const short8*)&Ks[kb1 + c * 1024];
            f32x4 S = {0.f, 0.f, 0.f, 0.f};
            S = mfma16(ak0, bq0, S);  // S^T: rows=key, cols=q
            S = mfma16(ak1, bq1, S);
            float4 mkv = *(const float4*)&mks[c * 16 + quad * 4];
            float p[4];
            #pragma unroll
            for (int r = 0; r < 4; r++) {
                float mk = (r == 0) ? mkv.x : (r == 1) ? mkv.y : (r == 2) ? mkv.z : mkv.w;
                float xf = mq1024 * mk;       // in [0, 1024)
                int i = (int)xf;
                float fr = FRACT(xf);
                float2 pe = ptab[i];
                float gp = fmaf(fr, pe.y, pe.x);     // gate * 0.125 * log2e
                p[r] = EXPB(S[r] * gp);
            }
            ls0 += p[0]; ls1 += p[1]; ls2 += p[2]; ls3 += p[3];
            *(uint2*)&PsW[pw + c * 16] = make_uint2(pack_bf16(p[0], p[1]), pack_bf16(p[2], p[3]));
        }

        // PV: O^T[d][q] += V^T[d][k] * P[q][k]
        #pragma unroll
        for (int kc = 0; kc < 2; kc++) {
            short8 bp = *(const short8*)&PsW[prd + kc * 32];
            const int vb = (kc == 0) ? kb0 : kb1;
            #pragma unroll
            for (int dt = 0; dt < 4; dt++) {
                short8 av = *(const short8*)&Vs[vb + dt * 1024];
                O[dt] = mfma16(av, bp, O[dt]);
            }
        }
    }

    float lsum = (ls0 + ls1) + (ls2 + ls3);
    lsum += __shfl_xor(lsum, 16);
    lsum += __shfl_xor(lsum, 32);
    float sc = mw / lsum;

    u16* aor = AO + ((size_t)(b * NSEQ) + qrow + l15) * DIM + h * HDIM + quad * 4;
    #pragma unroll
    for (int dt = 0; dt < 4; dt++) {
        *(uint2*)(aor + dt * 16) = make_uint2(pack_bf16(O[dt][0] * sc, O[dt][1] * sc),
                                              pack_bf16(O[dt][2] * sc, O[dt][3] * sc));
    }
}

// ---------------- output projection GEMM (128x64 tiles) ----------------
__global__ __launch_bounds__(256) void gemm_proj(const u16* __restrict__ A,
                                                 const u16* __restrict__ BT,
                                                 const float* __restrict__ bias,
                                                 float* __restrict__ outp) {
    __shared__ __align__(16) u16 As[128 * 32];
    __shared__ __align__(16) u16 Bs[64 * 32];
    const int bm = blockIdx.y * 128, bn = blockIdx.x * 64;
    const int t = threadIdx.x;
    const int lane = t & 63, wave = t >> 6;
    const int l15 = lane & 15, quad = lane >> 4;
    const int wm = wave * 32;

    const u16* ga = A + (size_t)(bm + (t >> 2)) * DIM + (t & 3) * 8;
    const u16* gb = BT + (size_t)(bn + (t >> 2)) * DIM + (t & 3) * 8;
    u16* la = As + wave * 512;
    u16* lb = Bs + wave * 512;

    f32x4 acc[2][4] = {};
    for (int k0 = 0; k0 < DIM; k0 += 32) {
        __syncthreads();
        glds16(ga, la);
        glds16(ga + (size_t)64 * DIM, la + 2048);
        glds16(gb, lb);
        ga += 32; gb += 32;
        __syncthreads();
        short8 af[2], bf[4];
        #pragma unroll
        for (int i = 0; i < 2; i++) af[i] = *(const short8*)&As[(wm + i * 16 + l15) * 32 + quad * 8];
        #pragma unroll
        for (int j = 0; j < 4; j++) bf[j] = *(const short8*)&Bs[(j * 16 + l15) * 32 + quad * 8];
        #pragma unroll
        for (int i = 0; i < 2; i++)
            #pragma unroll
            for (int j = 0; j < 4; j++)
                acc[i][j] = mfma16(af[i], bf[j], acc[i][j]);
    }

    #pragma unroll
    for (int i = 0; i < 2; i++) {
        int mr = bm + wm + i * 16 + quad * 4;
        #pragma unroll
        for (int j = 0; j < 4; j++) {
            int ncol = bn + j * 16 + l15;
            float bb = bias[ncol];
            #pragma unroll
            for (int r = 0; r < 4; r++)
                outp[(size_t)(mr + r) * DIM + ncol] = acc[i][j][r] + bb;
        }
    }
}

// ---------------- launch ----------------
extern "C" void kernel_launch(void* const* d_in, const int* in_sizes, int n_in,
                              void* d_out, int out_size, void* d_ws, size_t ws_size,
                              hipStream_t stream) {
    const float* x            = (const float*)d_in[0];
    const float* masks        = (const float*)d_in[1];
    const float* lambda_r     = (const float*)d_in[2];
    const float* theta_r      = (const float*)d_in[3];
    const float* mask_weights = (const float*)d_in[4];
    const float* qkv_w        = (const float*)d_in[5];
    const float* qkv_b        = (const float*)d_in[6];
    const float* proj_w       = (const float*)d_in[7];
    const float* proj_b       = (const float*)d_in[8];
    float* outp = (float*)d_out;

    const size_t SZH = (size_t)NB * NH * NSEQ * HDIM;  // 3.1M u16
    u16* xb    = (u16*)d_ws;                           // 4096*768 (also reused as ao)
    u16* wqkvT = xb + (size_t)4096 * 768;
    u16* wprT  = wqkvT + (size_t)2304 * 768;
    u16* qg    = wprT + (size_t)768 * 768;
    u16* kg    = qg + SZH;
    u16* vtmp  = kg + SZH;
    u16* vt    = vtmp + SZH;
    u16* ao    = xb;  // alias: xb dead after gemm_qkv

    convert_x<<<dim3((4096 * 768) / (4 * 256)), 256, 0, stream>>>(x, xb);
    transpose_to_bf16<<<dim3(2304 / 32, 768 / 32), 256, 0, stream>>>(qkv_w, wqkvT, 768, 2304);
    transpose_to_bf16<<<dim3(768 / 32, 768 / 32), 256, 0, stream>>>(proj_w, wprT, 768, 768);
    gemm_qkv<<<dim3(2304 / 128, 4096 / 128), 256, 0, stream>>>(xb, wqkvT, qkv_b, qg, kg, vtmp);
    vtrans<<<dim3(NSEQ / 64, NB * NH), 256, 0, stream>>>(vtmp, vt);
    attn_kernel<<<dim3(NSEQ / 64, NB * NH), 256, 0, stream>>>(qg, kg, vt, masks, lambda_r,
                                                              theta_r, mask_weights, ao);
    gemm_proj<<<dim3(768 / 64, 4096 / 128), 256, 0, stream>>>(ao, wprT, proj_b, outp);
}